// Round 1
// baseline (106.198 us; speedup 1.0000x reference)
//
#include <hip/hip_runtime.h>

#define G_TOTAL 16384            // 128 x 128 grid points
#define NPTS    8192             // context points
#define SPLIT   64               // split-K groups (atomic S_eff, same as proven kernel)
#define CHUNK   (NPTS / SPLIT)   // 128 context points per block
#define CI      64               // staged sub-chunk (2 phases per block)
#define NPH     (CHUNK / CI)
#define BK      16               // k rows per block
#define KBANDS  (128 / BK)       // 8
#define BLOCK   256

// Raw v_exp_f32 — args are in [-61, 0]: no denormal/range fixup needed.
__device__ __forceinline__ float fast_exp2(float x) {
#if __has_builtin(__builtin_amdgcn_exp2f)
    return __builtin_amdgcn_exp2f(x);
#else
    float r; asm("v_exp_f32 %0, %1" : "=v"(r) : "v"(x)); return r;
#endif
}

// ---------------------------------------------------------------------------
// Factorized-Gaussian rank-K kernel.
//   w(j,k,i) = exp2(-(s dx)^2 - (s dy)^2) = Ex(j,i) * Ey(k,i)
// Per 64-pt sub-chunk, stage in LDS:
//   ExT[tc][i*4+e]  : Ex for j = tc*4+e           (32 x 260, padded row)
//   Ey3[i][k*3+c]   : {Ey, Ey*y0, Ey*y1}          (64 x 48)
// Each thread owns a 4j x 2k x 3ch register tile (24 accumulators) and does
// 24 fma per staged i — 3 fma per output pair vs 1 exp + 6 VALU before.
// Total exps drop 134M -> ~9M; fma floor ~5 us.
// Grid: (SPLIT=64 chunks) x (KBANDS=8) = 512 blocks, 2 blocks/CU (45.5 KB LDS),
// atomics unchanged at 3.1M (6 per grid point per split group).
// ---------------------------------------------------------------------------
__global__ __launch_bounds__(BLOCK, 2) void enc_factored_kernel(
    const float* __restrict__ X,   // (8192, 2) positions
    const float* __restrict__ Y,   // (8192, 2) labels
    float* __restrict__ out)       // (3, 16384) accumulators (poison ~ -3e-13)
{
    __shared__ __align__(16) float ExT[32][CI * 4 + 4];  // +4 pad: 2-way banks
    __shared__ __align__(16) float Ey3[CI][BK * 3];

    const int t     = threadIdx.x;
    const int kb    = blockIdx.y * BK;       // k band base
    const int cbase = blockIdx.x * CHUNK;    // context chunk base

    const float s    = 0.84932184f;          // sqrt(0.5 * log2(e))
    const float step = 4.0f / 127.0f;
    const float ss   = step * s;

    const float2* X2 = (const float2*)X;
    const float2* Y2 = (const float2*)Y;

    // main-loop identity: 32 j-frags x 8 k-pairs
    const int tc = t & 31;                   // j frag: j = tc*4 + tj
    const int tr = t >> 5;                   // k pair: k = kb + tr*2 + tk

    float acc[24];
#pragma unroll
    for (int z = 0; z < 24; ++z) acc[z] = 0.0f;

    // stage identities
    const int   iis = t >> 5;                              // Ex: 8 i's each
    const float gj0 = (-2.0f + step * (float)(tc * 4)) * s;
    const int   ks  = t & 15;                              // Ey: k row
    const int   iqs = t >> 4;                              // Ey: 4 i's each
    const float gy  = (2.0f - step * (float)(kb + ks)) * s;

    for (int ph = 0; ph < NPH; ++ph) {
        const int c0 = cbase + ph * CI;
        if (ph) __syncthreads();             // readers of previous phase done

        // ---- stage Ex: 128 j x 64 i, 32 exps/thread
#pragma unroll
        for (int q = 0; q < 8; ++q) {
            const int   i  = iis * 8 + q;
            const float sx = X2[c0 + i].x * s;
            const float b  = gj0 - sx;
            float4 v;
            v.x = fast_exp2(-b * b);
            const float d1 = b + ss;        v.y = fast_exp2(-d1 * d1);
            const float d2 = b + 2.f * ss;  v.z = fast_exp2(-d2 * d2);
            const float d3 = b + 3.f * ss;  v.w = fast_exp2(-d3 * d3);
            *(float4*)&ExT[tc][i * 4] = v;
        }
        // ---- stage Ey channels: 16 k x 64 i, 4 exps/thread
#pragma unroll
        for (int p = 0; p < 4; ++p) {
            const int    i  = iqs * 4 + p;
            const float  sy = X2[c0 + i].y * s;
            const float2 yv = Y2[c0 + i];
            const float  d  = gy - sy;
            const float  e  = fast_exp2(-d * d);
            Ey3[i][ks * 3 + 0] = e;
            Ey3[i][ks * 3 + 1] = e * yv.x;
            Ey3[i][ks * 3 + 2] = e * yv.y;
        }
        __syncthreads();

        // ---- rank-1 accumulation: 24 fma per i
#pragma unroll 8
        for (int i = 0; i < CI; ++i) {
            const float4 a  = *(const float4*)&ExT[tc][i * 4];
            const float2 b0 = *(const float2*)&Ey3[i][tr * 6 + 0]; // E(k0), E(k0)y0
            const float2 b1 = *(const float2*)&Ey3[i][tr * 6 + 2]; // E(k0)y1, E(k1)
            const float2 b2 = *(const float2*)&Ey3[i][tr * 6 + 4]; // E(k1)y0, E(k1)y1
            const float av[4] = {a.x, a.y, a.z, a.w};
#pragma unroll
            for (int tj = 0; tj < 4; ++tj) {
                acc[tj*6+0] = fmaf(av[tj], b0.x, acc[tj*6+0]);
                acc[tj*6+1] = fmaf(av[tj], b0.y, acc[tj*6+1]);
                acc[tj*6+2] = fmaf(av[tj], b1.x, acc[tj*6+2]);
                acc[tj*6+3] = fmaf(av[tj], b1.y, acc[tj*6+3]);
                acc[tj*6+4] = fmaf(av[tj], b2.x, acc[tj*6+4]);
                acc[tj*6+5] = fmaf(av[tj], b2.y, acc[tj*6+5]);
            }
        }
    }

    // ---- epilogue: 24 atomics/thread (3.1M total, same as proven baseline)
    const int j0 = tc * 4;
    const int k0 = kb + tr * 2;
#pragma unroll
    for (int tj = 0; tj < 4; ++tj) {
        const int g0 = k0 * 128 + j0 + tj;
        const int g1 = g0 + 128;
        atomicAdd(&out[g0],               acc[tj*6+0]);
        atomicAdd(&out[G_TOTAL + g0],     acc[tj*6+1]);
        atomicAdd(&out[2 * G_TOTAL + g0], acc[tj*6+2]);
        atomicAdd(&out[g1],               acc[tj*6+3]);
        atomicAdd(&out[G_TOTAL + g1],     acc[tj*6+4]);
        atomicAdd(&out[2 * G_TOTAL + g1], acc[tj*6+5]);
    }
}

// ---------------------------------------------------------------------------
// Normalize smoothing channels by density channel, in place.
// ---------------------------------------------------------------------------
__global__ __launch_bounds__(256) void normalize_kernel(float* __restrict__ out) {
    int g = blockIdx.x * 256 + threadIdx.x;
    float inv = 1.0f / out[g];
    out[G_TOTAL + g]     *= inv;
    out[2 * G_TOTAL + g] *= inv;
}

// ---------------------------------------------------------------------------
extern "C" void kernel_launch(void* const* d_in, const int* in_sizes, int n_in,
                              void* d_out, int out_size, void* d_ws, size_t ws_size,
                              hipStream_t stream) {
    const float* X = (const float*)d_in[0];
    const float* Y = (const float*)d_in[1];
    float* out = (float*)d_out;

    dim3 grid(SPLIT, KBANDS);    // (64, 8) = 512 blocks of 256
    enc_factored_kernel<<<grid, BLOCK, 0, stream>>>(X, Y, out);
    normalize_kernel<<<G_TOTAL / 256, 256, 0, stream>>>(out);
}

// Round 2
// 89.772 us; speedup vs baseline: 1.1830x; 1.1830x over previous
//
#include <hip/hip_runtime.h>

#define G_TOTAL 16384            // 128 x 128 grid points
#define NPTS    8192             // context points
#define CI      64               // context points per block
#define SPLIT   (NPTS / CI)      // 128 split-K groups
#define BJ      64               // j (x) extent per block
#define BK      32               // k (y) extent per block
#define NTILE   8                // (128/BJ) * (128/BK) = 2 * 4
#define BLOCK   256
#define TILE_ELEMS   (BJ * BK * 3)              // 6144 floats per block
#define PART_TILE_STRIDE (SPLIT * TILE_ELEMS)   // floats per (jt,kt) tile in ws

// Raw v_exp_f32 — args are in [-47, 0]: no denormal/range fixup needed.
__device__ __forceinline__ float fast_exp2(float x) {
#if __has_builtin(__builtin_amdgcn_exp2f)
    return __builtin_amdgcn_exp2f(x);
#else
    float r; asm("v_exp_f32 %0, %1" : "=v"(r) : "v"(x)); return r;
#endif
}

// ---------------------------------------------------------------------------
// Factorized-Gaussian rank-K kernel, v2.
//   w(j,k,i) = Ex(j,i) * Ey(k,i),  channels = {1, y0(i), y1(i)}
// R1 post-mortem: 512 blocks (2 waves/SIMD) + 3.1M device-scope atomics
// (FETCH 105MB of RMW line-bouncing) left VALUBusy at 10%. v2:
//   * grid = 128 splits x 8 tiles = 1024 blocks -> 4 blocks/CU, 4 waves/SIMD
//   * LDS 25.3KB: Ey stored unexpanded (K floats/i, channels built with 4
//     regs-muls from the shared (y0,y1) broadcast) -> VALU:LDS = 2.8:1
//   * no atomics: coalesced partial stores to ws + fused reduce/normalize
// Per thread: 4j x 2k x 3c = 24 accumulators, 28 VALU + 3 LDS reads per i.
// ---------------------------------------------------------------------------
__global__ __launch_bounds__(BLOCK, 4) void enc_factored2(
    const float* __restrict__ X,   // (8192, 2) positions
    const float* __restrict__ Y,   // (8192, 2) labels
    float* __restrict__ ws)        // partials: [8 tiles][128 s][6144]
{
    __shared__ __align__(16) float  ExT[16][CI * 4 + 4]; // +4 pad: 2-way banks
    __shared__ float  EyT[CI][BK];
    __shared__ float2 W2[CI];

    const int t    = threadIdx.x;
    const int s    = blockIdx.x;         // split index (64-pt chunk)
    const int tile = blockIdx.y;         // 0..7
    const int jt   = tile & 1;
    const int kt   = tile >> 1;
    const int c0   = s * CI;

    const float sc   = 0.84932184f;      // sqrt(0.5 * log2(e))
    const float step = 4.0f / 127.0f;
    const float ssc  = step * sc;

    const float2* X2 = (const float2*)X;
    const float2* Y2 = (const float2*)Y;

    // ---- stage context labels (broadcast source for channel weights)
    if (t < CI) W2[t] = Y2[c0 + t];

    // ---- stage Ex: 64j x 64i, 16 exps/thread (lanes grouped by tc)
    {
        const int   tcx = t & 15;
        const int   i0  = (t >> 4) * 4;
        const float gj0 = (-2.0f + step * (float)(jt * BJ + tcx * 4)) * sc;
#pragma unroll
        for (int q = 0; q < 4; ++q) {
            const int   i  = i0 + q;
            const float sx = X2[c0 + i].x * sc;
            const float b  = gj0 - sx;
            float4 v;
            v.x = fast_exp2(-b * b);
            const float d1 = b + ssc;        v.y = fast_exp2(-d1 * d1);
            const float d2 = b + 2.f * ssc;  v.z = fast_exp2(-d2 * d2);
            const float d3 = b + 3.f * ssc;  v.w = fast_exp2(-d3 * d3);
            *(float4*)&ExT[tcx][i * 4] = v;
        }
    }
    // ---- stage Ey: 32k x 64i, 8 exps/thread
    {
        const int   kk = t & 31;
        const int   i0 = (t >> 5) * 8;
        const float gy = (2.0f - step * (float)(kt * BK + kk)) * sc;
#pragma unroll
        for (int p = 0; p < 8; ++p) {
            const int   i  = i0 + p;
            const float sy = X2[c0 + i].y * sc;
            const float d  = gy - sy;
            EyT[i][kk] = fast_exp2(-d * d);
        }
    }
    __syncthreads();

    // ---- rank-1 accumulation: thread owns j = tc*4+tj, k = tr*2+u
    const int tc = t & 15;
    const int tr = t >> 4;

    float acc[24];                       // [tj][u][c]
#pragma unroll
    for (int z = 0; z < 24; ++z) acc[z] = 0.0f;

#pragma unroll 8
    for (int i = 0; i < CI; ++i) {
        const float4 a = *(const float4*)&ExT[tc][i * 4];   // per-lane b128
        const float2 e = *(const float2*)&EyT[i][tr * 2];   // broadcast b64
        const float2 w = W2[i];                             // uniform b64
        const float m0x = e.x * w.x, m0y = e.x * w.y;       // channel weights
        const float m1x = e.y * w.x, m1y = e.y * w.y;
        const float av[4] = {a.x, a.y, a.z, a.w};
#pragma unroll
        for (int tj = 0; tj < 4; ++tj) {
            acc[tj*6 + 0] = fmaf(av[tj], e.x, acc[tj*6 + 0]);
            acc[tj*6 + 1] = fmaf(av[tj], m0x, acc[tj*6 + 1]);
            acc[tj*6 + 2] = fmaf(av[tj], m0y, acc[tj*6 + 2]);
            acc[tj*6 + 3] = fmaf(av[tj], e.y, acc[tj*6 + 3]);
            acc[tj*6 + 4] = fmaf(av[tj], m1x, acc[tj*6 + 4]);
            acc[tj*6 + 5] = fmaf(av[tj], m1y, acc[tj*6 + 5]);
        }
    }

    // ---- coalesced partial store: base[q*256 + t], q = c*8 + u*4 + tj
    float* base = ws + (size_t)tile * PART_TILE_STRIDE + (size_t)s * TILE_ELEMS;
#pragma unroll
    for (int c = 0; c < 3; ++c)
#pragma unroll
        for (int u = 0; u < 2; ++u)
#pragma unroll
            for (int tj = 0; tj < 4; ++tj)
                base[((c * 8 + u * 4 + tj) * 256) + t] = acc[tj*6 + u*3 + c];
}

// ---------------------------------------------------------------------------
// Fused reduce + normalize: block (qlow, tile) sums its 256 outputs over the
// 128 splits for all 3 channels (same (k,j) across channels by construction),
// then writes out[g], out[G+g]/d, out[2G+g]/d with plain stores.
// ---------------------------------------------------------------------------
__global__ __launch_bounds__(256) void reduce_norm(
    const float* __restrict__ ws, float* __restrict__ out)
{
    const int t    = threadIdx.x;
    const int qlow = blockIdx.x;     // 0..7 : u*4 + tj
    const int tile = blockIdx.y;     // 0..7

    const float* p = ws + (size_t)tile * PART_TILE_STRIDE + qlow * 256 + t;
    float s0 = 0.f, s1 = 0.f, s2 = 0.f;
#pragma unroll 4
    for (int s = 0; s < SPLIT; ++s, p += TILE_ELEMS) {
        s0 += p[0];          // c = 0 plane (q = qlow)
        s1 += p[8 * 256];    // c = 1 plane (q = qlow + 8)
        s2 += p[16 * 256];   // c = 2 plane (q = qlow + 16)
    }

    const int u  = qlow >> 2, tj = qlow & 3;
    const int tc = t & 15,    tr = t >> 4;
    const int jl = tc * 4 + tj;
    const int kk = tr * 2 + u;
    const int jt = tile & 1,  kt = tile >> 1;
    const int g  = (kt * BK + kk) * 128 + jt * BJ + jl;

    const float inv = 1.0f / s0;
    out[g]              = s0;
    out[G_TOTAL + g]    = s1 * inv;
    out[2*G_TOTAL + g]  = s2 * inv;
}

// ---------------------------------------------------------------------------
extern "C" void kernel_launch(void* const* d_in, const int* in_sizes, int n_in,
                              void* d_out, int out_size, void* d_ws, size_t ws_size,
                              hipStream_t stream) {
    const float* X = (const float*)d_in[0];
    const float* Y = (const float*)d_in[1];
    float* out = (float*)d_out;
    float* ws  = (float*)d_ws;

    dim3 grid(SPLIT, NTILE);     // (128, 8) = 1024 blocks, 4 blocks/CU
    enc_factored2<<<grid, BLOCK, 0, stream>>>(X, Y, ws);

    dim3 rgrid(8, 8);            // 64 blocks
    reduce_norm<<<rgrid, BLOCK, 0, stream>>>(ws, out);
}